// Round 1
// baseline (246.261 us; speedup 1.0000x reference)
//
#include <hip/hip_runtime.h>
#include <math.h>

#define UNITS 80
#define LATENT 128
#define IN_DIM 256
#define BATCH 8192
#define SEQ 256
#define G 320           // 4*UNITS
#define H2 160          // 2*UNITS

#define NCB 256         // compute blocks (32 rows each)
#define NWB 2048        // writer blocks
#define TPB 640         // 10 waves
#define ROWS 32

__device__ __forceinline__ float sigf(float v) {
    return 1.0f / (1.0f + __expf(-v));
}

// ---------------------------------------------------------------------------
// Kernel 1: yc = decode_step(ones(128)). Input all-ones => z = colsum(K) + b.
// One block, 320 threads (one per gate column).
// ---------------------------------------------------------------------------
__global__ void yc_kernel(const float* __restrict__ Kf, const float* __restrict__ bf,
                          const float* __restrict__ Kb, const float* __restrict__ bb,
                          const float* __restrict__ K1, const float* __restrict__ b1,
                          float* __restrict__ yc) {
    __shared__ float z[G];
    __shared__ float h[H2];
    int t = threadIdx.x;   // 0..319

    // forward LSTM, input = ones
    float acc = bf[t];
    for (int l = 0; l < LATENT; ++l) acc += Kf[l * G + t];
    z[t] = acc;
    __syncthreads();
    float hv = 0.f;
    if (t < UNITS) hv = sigf(z[240 + t]) * sigf(z[t]) * fmaxf(z[160 + t], 0.f);
    __syncthreads();                 // all reads of z done
    if (t < UNITS) h[t] = hv;

    // backward LSTM, input = ones
    acc = bb[t];
    for (int l = 0; l < LATENT; ++l) acc += Kb[l * G + t];
    z[t] = acc;
    __syncthreads();
    if (t < UNITS) hv = sigf(z[240 + t]) * sigf(z[t]) * fmaxf(z[160 + t], 0.f);
    __syncthreads();
    if (t < UNITS) h[UNITS + t] = hv;
    __syncthreads();                 // h fully written

    // output LSTM on h (160)
    acc = b1[t];
    for (int l = 0; l < H2; ++l) acc += h[l] * K1[l * G + t];
    z[t] = acc;
    __syncthreads();
    if (t < UNITS) yc[t] = sigf(z[240 + t]) * sigf(z[t]) * fmaxf(z[160 + t], 0.f);
}

// ---------------------------------------------------------------------------
// Kernel 2 (fused): blocks [0, NCB) compute y0 for 32 rows each and write the
// s=0 slices; blocks [NCB, NCB+NWB) broadcast yc into the s>=1 region.
// ---------------------------------------------------------------------------
__global__ __launch_bounds__(TPB)
void main_kernel(const float* __restrict__ x,
                 const float* __restrict__ Wl, const float* __restrict__ bl,
                 const float* __restrict__ Kf, const float* __restrict__ bf,
                 const float* __restrict__ Kb, const float* __restrict__ bb,
                 const float* __restrict__ K1, const float* __restrict__ b1,
                 const float* __restrict__ yc,
                 float* __restrict__ out) {
    // union region: x tile (32*256 f32 = 32KB) first, then h tile (32*160 = 20KB)
    __shared__ float smemA[ROWS * IN_DIM];
    __shared__ float lat_s[ROWS * LATENT];   // 16KB
    __shared__ float4 yc4s[UNITS / 4];       // 320B

    int t = threadIdx.x;
    int blk = blockIdx.x;

    if (blk >= NCB) {
        // ---------------- writer path: out[:, 1:, :] = yc ----------------
        if (t < UNITS / 4) yc4s[t] = ((const float4*)yc)[t];
        __syncthreads();
        float4* out4 = (float4*)out;
        const int per_b = (SEQ - 1) * UNITS / 4;         // 5100 float4 per batch row
        const int total = BATCH * per_b;                 // 41,779,200 (< 2^31)
        const int stride = NWB * TPB;
        for (int i = (blk - NCB) * TPB + t; i < total; i += stride) {
            int b = i / per_b;
            int r = i - b * per_b;
            out4[b * (SEQ * UNITS / 4) + (UNITS / 4) + r] = yc4s[r % (UNITS / 4)];
        }
        return;
    }

    // ---------------- compute path: y0 for rows [b0, b0+32) ----------------
    const int b0 = blk * ROWS;
    float* xs = smemA;                        // [32][256]
    float* h_s = smemA;                       // [32][160] (reuses xs region)

    // stage x tile
    {
        const float4* xg = (const float4*)(x + (size_t)b0 * IN_DIM);
        float4* xs4 = (float4*)xs;
        for (int i = t; i < ROWS * IN_DIM / 4; i += TPB) xs4[i] = xg[i];
    }
    __syncthreads();

    // lat = x @ W_lat + b_lat   (512 active threads: 128 cols x 4 rowgroups of 8)
    if (t < 512) {
        int col = t & 127;
        int rg  = t >> 7;                     // 0..3
        float acc[8];
#pragma unroll
        for (int r = 0; r < 8; ++r) acc[r] = 0.f;
        for (int l = 0; l < IN_DIM; ++l) {
            float w = Wl[l * LATENT + col];
#pragma unroll
            for (int r = 0; r < 8; ++r)
                acc[r] = fmaf(xs[(rg * 8 + r) * IN_DIM + l], w, acc[r]);
        }
        float bv = bl[col];
#pragma unroll
        for (int r = 0; r < 8; ++r) lat_s[(rg * 8 + r) * LATENT + col] = acc[r] + bv;
    }
    __syncthreads();   // lat ready; xs region free for h

    // per-thread mapping for the gate matmuls: unit u, rowgroup of 4 rows
    const int u  = t % UNITS;   // 0..79
    const int rg = t / UNITS;   // 0..7

    // forward LSTM gates (i, c, o; f is dead: c0 = 0)
    {
        float ai[4] = {0,0,0,0}, ac[4] = {0,0,0,0}, ao[4] = {0,0,0,0};
        for (int k = 0; k < LATENT; ++k) {
            float wi = Kf[k * G + u];
            float wc = Kf[k * G + 160 + u];
            float wo = Kf[k * G + 240 + u];
#pragma unroll
            for (int r = 0; r < 4; ++r) {
                float lv = lat_s[(rg * 4 + r) * LATENT + k];
                ai[r] = fmaf(lv, wi, ai[r]);
                ac[r] = fmaf(lv, wc, ac[r]);
                ao[r] = fmaf(lv, wo, ao[r]);
            }
        }
        float bi = bf[u], bc = bf[160 + u], bo = bf[240 + u];
#pragma unroll
        for (int r = 0; r < 4; ++r) {
            int row = rg * 4 + r;
            h_s[row * H2 + u] =
                sigf(ao[r] + bo) * sigf(ai[r] + bi) * fmaxf(ac[r] + bc, 0.f);
        }
    }
    // backward LSTM gates
    {
        float ai[4] = {0,0,0,0}, ac[4] = {0,0,0,0}, ao[4] = {0,0,0,0};
        for (int k = 0; k < LATENT; ++k) {
            float wi = Kb[k * G + u];
            float wc = Kb[k * G + 160 + u];
            float wo = Kb[k * G + 240 + u];
#pragma unroll
            for (int r = 0; r < 4; ++r) {
                float lv = lat_s[(rg * 4 + r) * LATENT + k];
                ai[r] = fmaf(lv, wi, ai[r]);
                ac[r] = fmaf(lv, wc, ac[r]);
                ao[r] = fmaf(lv, wo, ao[r]);
            }
        }
        float bi = bb[u], bc = bb[160 + u], bo = bb[240 + u];
#pragma unroll
        for (int r = 0; r < 4; ++r) {
            int row = rg * 4 + r;
            h_s[row * H2 + UNITS + u] =
                sigf(ao[r] + bo) * sigf(ai[r] + bi) * fmaxf(ac[r] + bc, 0.f);
        }
    }
    __syncthreads();   // h fully written

    // output LSTM: y0 = gates(h @ K_1 + b_1); write s=0 slice
    {
        float ai[4] = {0,0,0,0}, ac[4] = {0,0,0,0}, ao[4] = {0,0,0,0};
        for (int k = 0; k < H2; ++k) {
            float wi = K1[k * G + u];
            float wc = K1[k * G + 160 + u];
            float wo = K1[k * G + 240 + u];
#pragma unroll
            for (int r = 0; r < 4; ++r) {
                float lv = h_s[(rg * 4 + r) * H2 + k];
                ai[r] = fmaf(lv, wi, ai[r]);
                ac[r] = fmaf(lv, wc, ac[r]);
                ao[r] = fmaf(lv, wo, ao[r]);
            }
        }
        float bi = b1[u], bc = b1[160 + u], bo = b1[240 + u];
#pragma unroll
        for (int r = 0; r < 4; ++r) {
            int row = rg * 4 + r;
            float y = sigf(ao[r] + bo) * sigf(ai[r] + bi) * fmaxf(ac[r] + bc, 0.f);
            out[(size_t)(b0 + row) * SEQ * UNITS + u] = y;
        }
    }
}

extern "C" void kernel_launch(void* const* d_in, const int* in_sizes, int n_in,
                              void* d_out, int out_size, void* d_ws, size_t ws_size,
                              hipStream_t stream) {
    const float* x   = (const float*)d_in[0];
    // d_in[1] = size (scalar, fixed 256)
    const float* Wl  = (const float*)d_in[2];
    const float* bl  = (const float*)d_in[3];
    const float* Kf  = (const float*)d_in[4];
    const float* bf  = (const float*)d_in[5];
    const float* Kb  = (const float*)d_in[6];
    const float* bb  = (const float*)d_in[7];
    const float* K1  = (const float*)d_in[8];
    const float* b1  = (const float*)d_in[9];
    float* out = (float*)d_out;
    float* yc  = (float*)d_ws;   // 80 floats

    yc_kernel<<<1, G, 0, stream>>>(Kf, bf, Kb, bb, K1, b1, yc);
    main_kernel<<<NCB + NWB, TPB, 0, stream>>>(x, Wl, bl, Kf, bf, Kb, bb, K1, b1, yc, out);
}